// Round 1
// baseline (1234.085 us; speedup 1.0000x reference)
//
#include <hip/hip_runtime.h>

// GCN: N=100000 nodes, E=1600000 edges, C_IN=128, C_HID=128, C_OUT=64.
// Pipeline per call:
//   detect int32/int64 edge layout -> degree count -> dinv -> exclusive scan ->
//   CSR fill -> [gemm -> aggregate] x3 -> z = h2@mlp_w1 -> per-edge MLP.
// Workspace use: ~117 MB (two [N,128] fp32 ping-pong buffers + CSR arrays).

// ---------------- edge accessors (int32 vs int64 runtime flag) ----------------
// flag==1 -> int32 layout (some odd 32-bit word nonzero); flag==0 -> int64.
__device__ __forceinline__ int edge_at(const int* __restrict__ ei, long long idx, int is32) {
    return is32 ? ei[idx] : ei[2 * idx];
}

__global__ __launch_bounds__(256) void k_detect(const int* __restrict__ ei, int E, int* __restrict__ flag) {
    int i = blockIdx.x * 256 + threadIdx.x;
    if (i < E) {
        if (ei[2 * i + 1] != 0) atomicOr(flag, 1);
    }
}

__global__ __launch_bounds__(256) void k_count(const int* __restrict__ ei, int E, int* __restrict__ cnt,
                                               const int* __restrict__ flag) {
    int is32 = *flag;
    int e = blockIdx.x * 256 + threadIdx.x;
    if (e < E) {
        int d = edge_at(ei, (long long)E + e, is32);
        atomicAdd(&cnt[d], 1);
    }
}

__global__ __launch_bounds__(256) void k_dinv(const int* __restrict__ cnt, float* __restrict__ dinv, int N) {
    int i = blockIdx.x * 256 + threadIdx.x;
    if (i < N) dinv[i] = rsqrtf((float)(cnt[i] + 1));  // +1: self-loop
}

// Exclusive scan of cnt within 1024-element chunks; block sums out.
__global__ __launch_bounds__(256) void k_scan_local(const int* __restrict__ cnt, int N,
                                                    int* __restrict__ offs, int* __restrict__ bsums) {
    __shared__ int wsum[4];
    int t = threadIdx.x;
    int lane = t & 63, wid = t >> 6;
    int gbase = blockIdx.x * 1024 + t * 4;
    int v0 = 0, v1 = 0, v2 = 0, v3 = 0;
    if (gbase + 0 < N) v0 = cnt[gbase + 0];
    if (gbase + 1 < N) v1 = cnt[gbase + 1];
    if (gbase + 2 < N) v2 = cnt[gbase + 2];
    if (gbase + 3 < N) v3 = cnt[gbase + 3];
    int tot = v0 + v1 + v2 + v3;
    int x = tot;
#pragma unroll
    for (int d = 1; d < 64; d <<= 1) {
        int y = __shfl_up(x, d);
        if (lane >= d) x += y;
    }
    if (lane == 63) wsum[wid] = x;
    __syncthreads();
    int wbase = 0;
#pragma unroll
    for (int w = 0; w < 4; w++)
        if (w < wid) wbase += wsum[w];
    int ex = wbase + x - tot;  // exclusive within chunk
    if (gbase + 0 < N) offs[gbase + 0] = ex;
    if (gbase + 1 < N) offs[gbase + 1] = ex + v0;
    if (gbase + 2 < N) offs[gbase + 2] = ex + v0 + v1;
    if (gbase + 3 < N) offs[gbase + 3] = ex + v0 + v1 + v2;
    if (t == 255) bsums[blockIdx.x] = wbase + x;
}

__global__ void k_scan_bsums(int* __restrict__ bsums, int nb) {
    int run = 0;
    for (int i = 0; i < nb; i++) {
        int v = bsums[i];
        bsums[i] = run;
        run += v;
    }
}

__global__ __launch_bounds__(256) void k_scan_add(int* __restrict__ offs, const int* __restrict__ bsums, int N) {
    int i = blockIdx.x * 256 + threadIdx.x;
    if (i < N) offs[i] += bsums[i >> 10];
}

__global__ __launch_bounds__(256) void k_fill(const int* __restrict__ ei, int E,
                                              const int* __restrict__ offs, int* __restrict__ cursor,
                                              const float* __restrict__ dinv,
                                              int* __restrict__ csr_src, float* __restrict__ csr_w,
                                              const int* __restrict__ flag) {
    int is32 = *flag;
    int e = blockIdx.x * 256 + threadIdx.x;
    if (e < E) {
        int s = edge_at(ei, e, is32);
        int d = edge_at(ei, (long long)E + e, is32);
        int pos = offs[d] + atomicAdd(&cursor[d], 1);
        csr_src[pos] = s;
        csr_w[pos] = dinv[s];
    }
}

// ---------------- dense GEMM: Y[N,COUT] = X[N,CIN] @ W[CIN,COUT] (fp32) ----------------
// Block: 256 threads, 64-row tile. X tile staged in LDS (contiguous rows -> linear copy).
template <int CIN, int COUT>
__global__ __launch_bounds__(256) void k_gemm(const float* __restrict__ X, const float* __restrict__ W,
                                              float* __restrict__ Y, int N) {
    constexpr int CT = COUT / 4;   // threads covering cols (float4 each)
    constexpr int RG = 256 / CT;   // row groups
    constexpr int RPT = 64 / RG;   // rows per thread
    __shared__ float xs[64 * CIN];
    int t = threadIdx.x;
    int r0 = blockIdx.x * 64;
    int limit = (N - r0 < 64 ? N - r0 : 64) * CIN;
    for (int i = t * 4; i < 64 * CIN; i += 1024) {
        float4 v = make_float4(0.f, 0.f, 0.f, 0.f);
        if (i < limit) v = *(const float4*)&X[(size_t)r0 * CIN + i];
        *(float4*)&xs[i] = v;
    }
    __syncthreads();

    int ct = t % CT, rg = t / CT;
    float4 acc[RPT];
#pragma unroll
    for (int j = 0; j < RPT; j++) acc[j] = make_float4(0.f, 0.f, 0.f, 0.f);
    const float* wp = W + ct * 4;
    for (int k = 0; k < CIN; k += 4) {
        float4 w0 = *(const float4*)&wp[(size_t)(k + 0) * COUT];
        float4 w1 = *(const float4*)&wp[(size_t)(k + 1) * COUT];
        float4 w2 = *(const float4*)&wp[(size_t)(k + 2) * COUT];
        float4 w3 = *(const float4*)&wp[(size_t)(k + 3) * COUT];
#pragma unroll
        for (int j = 0; j < RPT; j++) {
            float4 a = *(const float4*)&xs[(rg * RPT + j) * CIN + k];
            acc[j].x += a.x * w0.x + a.y * w1.x + a.z * w2.x + a.w * w3.x;
            acc[j].y += a.x * w0.y + a.y * w1.y + a.z * w2.y + a.w * w3.y;
            acc[j].z += a.x * w0.z + a.y * w1.z + a.z * w2.z + a.w * w3.z;
            acc[j].w += a.x * w0.w + a.y * w1.w + a.z * w2.w + a.w * w3.w;
        }
    }
#pragma unroll
    for (int j = 0; j < RPT; j++) {
        int row = r0 + rg * RPT + j;
        if (row < N) *(float4*)&Y[(size_t)row * COUT + ct * 4] = acc[j];
    }
}

// ---------------- aggregation: H[i] = relu?(dinv_i * sum_j w_j*T[src_j] + dinv_i^2*T[i] + b) ----
// One wave per node. CSR entries batched 64-at-a-time into registers, broadcast via shfl.
template <int C, bool RELU>
__global__ __launch_bounds__(256) void k_aggregate(const float* __restrict__ T, const int* __restrict__ offs,
                                                   const int* __restrict__ cnt, const int* __restrict__ csr_src,
                                                   const float* __restrict__ csr_w, const float* __restrict__ dinv,
                                                   const float* __restrict__ bias, float* __restrict__ H, int N) {
    int gw = (blockIdx.x * 256 + threadIdx.x) >> 6;
    int l = threadIdx.x & 63;
    if (gw >= N) return;
    float acc0 = 0.f, acc1 = 0.f;
    int start = offs[gw], num = cnt[gw];
    for (int base = 0; base < num; base += 64) {
        int sv = 0;
        float wv = 0.f;
        if (base + l < num) {
            sv = csr_src[start + base + l];
            wv = csr_w[start + base + l];
        }
        int m = num - base;
        if (m > 64) m = 64;
        for (int j = 0; j < m; j++) {
            int s = __shfl(sv, j);
            float w = __shfl(wv, j);
            if constexpr (C == 128) {
                float2 tv = *(const float2*)&T[(size_t)s * C + l * 2];
                acc0 += w * tv.x;
                acc1 += w * tv.y;
            } else {
                acc0 += w * T[(size_t)s * C + l];
            }
        }
    }
    float di = dinv[gw];
    float di2 = di * di;
    if constexpr (C == 128) {
        float2 ts = *(const float2*)&T[(size_t)gw * C + l * 2];
        float o0 = di * acc0 + di2 * ts.x + bias[l * 2 + 0];
        float o1 = di * acc1 + di2 * ts.y + bias[l * 2 + 1];
        if (RELU) {
            o0 = fmaxf(o0, 0.f);
            o1 = fmaxf(o1, 0.f);
        }
        float2 o = make_float2(o0, o1);
        *(float2*)&H[(size_t)gw * C + l * 2] = o;
    } else {
        float o0 = di * acc0 + di2 * T[(size_t)gw * C + l] + bias[l];
        if (RELU) o0 = fmaxf(o0, 0.f);
        H[(size_t)gw * C + l] = o0;
    }
}

// ---------------- final per-edge MLP: y = relu(0.5*(z_s+z_d)+b1) @ w2 + b2 ----------------
// 16 lanes per edge, 4 features each; xor-shuffle reduce.
__global__ __launch_bounds__(256) void k_edge_mlp(const int* __restrict__ ei, int E,
                                                  const float* __restrict__ Z, const float* __restrict__ b1,
                                                  const float* __restrict__ w2, const float* __restrict__ b2,
                                                  float* __restrict__ out, const int* __restrict__ flag) {
    int is32 = *flag;
    long long t = (long long)blockIdx.x * 256 + threadIdx.x;
    int e = (int)(t >> 4);
    int l = (int)(t & 15);
    if (e >= E) return;
    int s = edge_at(ei, e, is32);
    int d = edge_at(ei, (long long)E + e, is32);
    float4 zs = *(const float4*)&Z[(size_t)s * 64 + l * 4];
    float4 zd = *(const float4*)&Z[(size_t)d * 64 + l * 4];
    float4 bb = *(const float4*)&b1[l * 4];
    float4 u;
    u.x = fmaxf(0.f, 0.5f * (zs.x + zd.x) + bb.x);
    u.y = fmaxf(0.f, 0.5f * (zs.y + zd.y) + bb.y);
    u.z = fmaxf(0.f, 0.5f * (zs.z + zd.z) + bb.z);
    u.w = fmaxf(0.f, 0.5f * (zs.w + zd.w) + bb.w);
    float4 wa = *(const float4*)&w2[l * 8];      // rows l*4, l*4+1 (both cols)
    float4 wb = *(const float4*)&w2[l * 8 + 4];  // rows l*4+2, l*4+3
    float y0 = u.x * wa.x + u.y * wa.z + u.z * wb.x + u.w * wb.z;
    float y1 = u.x * wa.y + u.y * wa.w + u.z * wb.y + u.w * wb.w;
#pragma unroll
    for (int m = 1; m < 16; m <<= 1) {
        y0 += __shfl_xor(y0, m);
        y1 += __shfl_xor(y1, m);
    }
    if (l == 0) out[(size_t)e * 2 + 0] = y0 + b2[0];
    else if (l == 1) out[(size_t)e * 2 + 1] = y1 + b2[1];
}

extern "C" void kernel_launch(void* const* d_in, const int* in_sizes, int n_in,
                              void* d_out, int out_size, void* d_ws, size_t ws_size,
                              hipStream_t stream) {
    const float* x = (const float*)d_in[0];
    const int* ei = (const int*)d_in[1];
    const float* W0 = (const float*)d_in[2];
    const float* b0 = (const float*)d_in[3];
    const float* W1 = (const float*)d_in[4];
    const float* b1 = (const float*)d_in[5];
    const float* W2 = (const float*)d_in[6];
    const float* b2 = (const float*)d_in[7];
    const float* mw1 = (const float*)d_in[8];
    const float* mb1 = (const float*)d_in[9];
    const float* mw2 = (const float*)d_in[10];
    const float* mb2 = (const float*)d_in[11];
    float* out = (float*)d_out;

    int N = in_sizes[0] / 128;
    int E = in_sizes[1] / 2;

    char* p = (char*)d_ws;
    auto alloc = [&](size_t bytes) {
        char* q = p;
        p += (bytes + 255) & ~size_t(255);
        return q;
    };
    float* bufA = (float*)alloc((size_t)N * 128 * 4);
    float* bufB = (float*)alloc((size_t)N * 128 * 4);
    int* cnt = (int*)alloc((size_t)N * 4);
    int* cursor = (int*)alloc((size_t)N * 4);
    int* offs = (int*)alloc((size_t)N * 4);
    float* dinv = (float*)alloc((size_t)N * 4);
    int* csr_src = (int*)alloc((size_t)E * 4);
    float* csr_w = (float*)alloc((size_t)E * 4);
    int* bsums = (int*)alloc(4096);
    int* flag = (int*)alloc(256);

    hipMemsetAsync(cnt, 0, (size_t)N * 4, stream);
    hipMemsetAsync(cursor, 0, (size_t)N * 4, stream);
    hipMemsetAsync(flag, 0, 4, stream);

    int gE = (E + 255) / 256;
    int gN = (N + 255) / 256;
    k_detect<<<gE, 256, 0, stream>>>(ei, E, flag);
    k_count<<<gE, 256, 0, stream>>>(ei, E, cnt, flag);
    k_dinv<<<gN, 256, 0, stream>>>(cnt, dinv, N);
    int nb = (N + 1023) / 1024;
    k_scan_local<<<nb, 256, 0, stream>>>(cnt, N, offs, bsums);
    k_scan_bsums<<<1, 1, 0, stream>>>(bsums, nb);
    k_scan_add<<<gN, 256, 0, stream>>>(offs, bsums, N);
    k_fill<<<gE, 256, 0, stream>>>(ei, E, offs, cursor, dinv, csr_src, csr_w, flag);

    int gG = (N + 63) / 64;
    int gA = (N * 4 + 3) / 4;  // N waves, 4 per block
    gA = (N + 3) / 4;

    // layer 0: t = x@W0 ; h0 = relu(agg(t)+b0)
    k_gemm<128, 128><<<gG, 256, 0, stream>>>(x, W0, bufA, N);
    k_aggregate<128, true><<<gA, 256, 0, stream>>>(bufA, offs, cnt, csr_src, csr_w, dinv, b0, bufB, N);
    // layer 1
    k_gemm<128, 128><<<gG, 256, 0, stream>>>(bufB, W1, bufA, N);
    k_aggregate<128, true><<<gA, 256, 0, stream>>>(bufA, offs, cnt, csr_src, csr_w, dinv, b1, bufB, N);
    // layer 2 (no relu)
    k_gemm<128, 64><<<gG, 256, 0, stream>>>(bufB, W2, bufA, N);
    k_aggregate<64, false><<<gA, 256, 0, stream>>>(bufA, offs, cnt, csr_src, csr_w, dinv, b2, bufB, N);
    // z = h2 @ mlp_w1 (linearity: ef@mlp_w1 = 0.5*(z_s+z_d))
    k_gemm<64, 64><<<gG, 256, 0, stream>>>(bufB, mw1, bufA, N);

    long long totalT = (long long)E * 16;
    int gM = (int)((totalT + 255) / 256);
    k_edge_mlp<<<gM, 256, 0, stream>>>(ei, E, bufA, mb1, mw2, mb2, out, flag);
}

// Round 2
// 1023.084 us; speedup vs baseline: 1.2062x; 1.2062x over previous
//
#include <hip/hip_runtime.h>

// GCN: N=100000 nodes, E=1600000 edges, C_IN=128, C_HID=128, C_OUT=64.
// Pipeline per call:
//   detect int32/int64 edge layout -> degree count -> dinv -> exclusive scan ->
//   CSR fill -> [gemm -> aggregate] x3 -> z = h2@mlp_w1 -> per-edge MLP.
// Workspace use: ~117 MB (two [N,128] fp32 ping-pong buffers + CSR arrays).

// ---------------- edge accessors (int32 vs int64 runtime flag) ----------------
// flag==1 -> int32 layout (some odd 32-bit word nonzero); flag==0 -> int64.
__device__ __forceinline__ int edge_at(const int* __restrict__ ei, long long idx, int is32) {
    return is32 ? ei[idx] : ei[2 * idx];
}

// Wave-reduced detect: OR odd words locally, __any per wave, <=1 atomic per wave.
// (R1: per-thread atomicOr on one word serialized 1.6M atomics -> 286us, 23% of total.)
__global__ __launch_bounds__(256) void k_detect(const int4* __restrict__ ei4, int nchunks,
                                                int* __restrict__ flag) {
    int acc = 0;
    for (int i = blockIdx.x * 256 + threadIdx.x; i < nchunks; i += gridDim.x * 256) {
        int4 v = ei4[i];
        acc |= v.y | v.w;
    }
    if (__any(acc != 0)) {
        if ((threadIdx.x & 63) == 0) atomicOr(flag, 1);
    }
}

__global__ __launch_bounds__(256) void k_count(const int* __restrict__ ei, int E, int* __restrict__ cnt,
                                               const int* __restrict__ flag) {
    int is32 = *flag;
    int e = blockIdx.x * 256 + threadIdx.x;
    if (e < E) {
        int d = edge_at(ei, (long long)E + e, is32);
        atomicAdd(&cnt[d], 1);
    }
}

__global__ __launch_bounds__(256) void k_dinv(const int* __restrict__ cnt, float* __restrict__ dinv, int N) {
    int i = blockIdx.x * 256 + threadIdx.x;
    if (i < N) dinv[i] = rsqrtf((float)(cnt[i] + 1));  // +1: self-loop
}

// Exclusive scan of cnt within 1024-element chunks; block sums out.
__global__ __launch_bounds__(256) void k_scan_local(const int* __restrict__ cnt, int N,
                                                    int* __restrict__ offs, int* __restrict__ bsums) {
    __shared__ int wsum[4];
    int t = threadIdx.x;
    int lane = t & 63, wid = t >> 6;
    int gbase = blockIdx.x * 1024 + t * 4;
    int v0 = 0, v1 = 0, v2 = 0, v3 = 0;
    if (gbase + 0 < N) v0 = cnt[gbase + 0];
    if (gbase + 1 < N) v1 = cnt[gbase + 1];
    if (gbase + 2 < N) v2 = cnt[gbase + 2];
    if (gbase + 3 < N) v3 = cnt[gbase + 3];
    int tot = v0 + v1 + v2 + v3;
    int x = tot;
#pragma unroll
    for (int d = 1; d < 64; d <<= 1) {
        int y = __shfl_up(x, d);
        if (lane >= d) x += y;
    }
    if (lane == 63) wsum[wid] = x;
    __syncthreads();
    int wbase = 0;
#pragma unroll
    for (int w = 0; w < 4; w++)
        if (w < wid) wbase += wsum[w];
    int ex = wbase + x - tot;  // exclusive within chunk
    if (gbase + 0 < N) offs[gbase + 0] = ex;
    if (gbase + 1 < N) offs[gbase + 1] = ex + v0;
    if (gbase + 2 < N) offs[gbase + 2] = ex + v0 + v1;
    if (gbase + 3 < N) offs[gbase + 3] = ex + v0 + v1 + v2;
    if (t == 255) bsums[blockIdx.x] = wbase + x;
}

__global__ void k_scan_bsums(int* __restrict__ bsums, int nb) {
    int run = 0;
    for (int i = 0; i < nb; i++) {
        int v = bsums[i];
        bsums[i] = run;
        run += v;
    }
}

__global__ __launch_bounds__(256) void k_scan_add(int* __restrict__ offs, const int* __restrict__ bsums, int N) {
    int i = blockIdx.x * 256 + threadIdx.x;
    if (i < N) offs[i] += bsums[i >> 10];
}

__global__ __launch_bounds__(256) void k_fill(const int* __restrict__ ei, int E,
                                              const int* __restrict__ offs, int* __restrict__ cursor,
                                              const float* __restrict__ dinv,
                                              int* __restrict__ csr_src, float* __restrict__ csr_w,
                                              const int* __restrict__ flag) {
    int is32 = *flag;
    int e = blockIdx.x * 256 + threadIdx.x;
    if (e < E) {
        int s = edge_at(ei, e, is32);
        int d = edge_at(ei, (long long)E + e, is32);
        int pos = offs[d] + atomicAdd(&cursor[d], 1);
        csr_src[pos] = s;
        csr_w[pos] = dinv[s];
    }
}

// ---------------- dense GEMM: Y[N,COUT] = X[N,CIN] @ W[CIN,COUT] (fp32) ----------------
// Block: 256 threads, 64-row tile. X tile staged in LDS (contiguous rows -> linear copy).
template <int CIN, int COUT>
__global__ __launch_bounds__(256) void k_gemm(const float* __restrict__ X, const float* __restrict__ W,
                                              float* __restrict__ Y, int N) {
    constexpr int CT = COUT / 4;   // threads covering cols (float4 each)
    constexpr int RG = 256 / CT;   // row groups
    constexpr int RPT = 64 / RG;   // rows per thread
    __shared__ float xs[64 * CIN];
    int t = threadIdx.x;
    int r0 = blockIdx.x * 64;
    int limit = (N - r0 < 64 ? N - r0 : 64) * CIN;
    for (int i = t * 4; i < 64 * CIN; i += 1024) {
        float4 v = make_float4(0.f, 0.f, 0.f, 0.f);
        if (i < limit) v = *(const float4*)&X[(size_t)r0 * CIN + i];
        *(float4*)&xs[i] = v;
    }
    __syncthreads();

    int ct = t % CT, rg = t / CT;
    float4 acc[RPT];
#pragma unroll
    for (int j = 0; j < RPT; j++) acc[j] = make_float4(0.f, 0.f, 0.f, 0.f);
    const float* wp = W + ct * 4;
    for (int k = 0; k < CIN; k += 4) {
        float4 w0 = *(const float4*)&wp[(size_t)(k + 0) * COUT];
        float4 w1 = *(const float4*)&wp[(size_t)(k + 1) * COUT];
        float4 w2 = *(const float4*)&wp[(size_t)(k + 2) * COUT];
        float4 w3 = *(const float4*)&wp[(size_t)(k + 3) * COUT];
#pragma unroll
        for (int j = 0; j < RPT; j++) {
            float4 a = *(const float4*)&xs[(rg * RPT + j) * CIN + k];
            acc[j].x += a.x * w0.x + a.y * w1.x + a.z * w2.x + a.w * w3.x;
            acc[j].y += a.x * w0.y + a.y * w1.y + a.z * w2.y + a.w * w3.y;
            acc[j].z += a.x * w0.z + a.y * w1.z + a.z * w2.z + a.w * w3.z;
            acc[j].w += a.x * w0.w + a.y * w1.w + a.z * w2.w + a.w * w3.w;
        }
    }
#pragma unroll
    for (int j = 0; j < RPT; j++) {
        int row = r0 + rg * RPT + j;
        if (row < N) *(float4*)&Y[(size_t)row * COUT + ct * 4] = acc[j];
    }
}

// ---------------- aggregation: H[i] = relu?(dinv_i * sum_j w_j*T[src_j] + dinv_i^2*T[i] + b) ----
// One wave per node. CSR entries batched 64-at-a-time into registers, broadcast via shfl.
template <int C, bool RELU>
__global__ __launch_bounds__(256) void k_aggregate(const float* __restrict__ T, const int* __restrict__ offs,
                                                   const int* __restrict__ cnt, const int* __restrict__ csr_src,
                                                   const float* __restrict__ csr_w, const float* __restrict__ dinv,
                                                   const float* __restrict__ bias, float* __restrict__ H, int N) {
    int gw = (blockIdx.x * 256 + threadIdx.x) >> 6;
    int l = threadIdx.x & 63;
    if (gw >= N) return;
    float acc0 = 0.f, acc1 = 0.f;
    int start = offs[gw], num = cnt[gw];
    for (int base = 0; base < num; base += 64) {
        int sv = 0;
        float wv = 0.f;
        if (base + l < num) {
            sv = csr_src[start + base + l];
            wv = csr_w[start + base + l];
        }
        int m = num - base;
        if (m > 64) m = 64;
        for (int j = 0; j < m; j++) {
            int s = __shfl(sv, j);
            float w = __shfl(wv, j);
            if constexpr (C == 128) {
                float2 tv = *(const float2*)&T[(size_t)s * C + l * 2];
                acc0 += w * tv.x;
                acc1 += w * tv.y;
            } else {
                acc0 += w * T[(size_t)s * C + l];
            }
        }
    }
    float di = dinv[gw];
    float di2 = di * di;
    if constexpr (C == 128) {
        float2 ts = *(const float2*)&T[(size_t)gw * C + l * 2];
        float o0 = di * acc0 + di2 * ts.x + bias[l * 2 + 0];
        float o1 = di * acc1 + di2 * ts.y + bias[l * 2 + 1];
        if (RELU) {
            o0 = fmaxf(o0, 0.f);
            o1 = fmaxf(o1, 0.f);
        }
        float2 o = make_float2(o0, o1);
        *(float2*)&H[(size_t)gw * C + l * 2] = o;
    } else {
        float o0 = di * acc0 + di2 * T[(size_t)gw * C + l] + bias[l];
        if (RELU) o0 = fmaxf(o0, 0.f);
        H[(size_t)gw * C + l] = o0;
    }
}

// ---------------- final per-edge MLP: y = relu(0.5*(z_s+z_d)+b1) @ w2 + b2 ----------------
// 16 lanes per edge, 4 features each; xor-shuffle reduce.
__global__ __launch_bounds__(256) void k_edge_mlp(const int* __restrict__ ei, int E,
                                                  const float* __restrict__ Z, const float* __restrict__ b1,
                                                  const float* __restrict__ w2, const float* __restrict__ b2,
                                                  float* __restrict__ out, const int* __restrict__ flag) {
    int is32 = *flag;
    long long t = (long long)blockIdx.x * 256 + threadIdx.x;
    int e = (int)(t >> 4);
    int l = (int)(t & 15);
    if (e >= E) return;
    int s = edge_at(ei, e, is32);
    int d = edge_at(ei, (long long)E + e, is32);
    float4 zs = *(const float4*)&Z[(size_t)s * 64 + l * 4];
    float4 zd = *(const float4*)&Z[(size_t)d * 64 + l * 4];
    float4 bb = *(const float4*)&b1[l * 4];
    float4 u;
    u.x = fmaxf(0.f, 0.5f * (zs.x + zd.x) + bb.x);
    u.y = fmaxf(0.f, 0.5f * (zs.y + zd.y) + bb.y);
    u.z = fmaxf(0.f, 0.5f * (zs.z + zd.z) + bb.z);
    u.w = fmaxf(0.f, 0.5f * (zs.w + zd.w) + bb.w);
    float4 wa = *(const float4*)&w2[l * 8];      // rows l*4, l*4+1 (both cols)
    float4 wb = *(const float4*)&w2[l * 8 + 4];  // rows l*4+2, l*4+3
    float y0 = u.x * wa.x + u.y * wa.z + u.z * wb.x + u.w * wb.z;
    float y1 = u.x * wa.y + u.y * wa.w + u.z * wb.y + u.w * wb.w;
#pragma unroll
    for (int m = 1; m < 16; m <<= 1) {
        y0 += __shfl_xor(y0, m);
        y1 += __shfl_xor(y1, m);
    }
    if (l == 0) out[(size_t)e * 2 + 0] = y0 + b2[0];
    else if (l == 1) out[(size_t)e * 2 + 1] = y1 + b2[1];
}

extern "C" void kernel_launch(void* const* d_in, const int* in_sizes, int n_in,
                              void* d_out, int out_size, void* d_ws, size_t ws_size,
                              hipStream_t stream) {
    const float* x = (const float*)d_in[0];
    const int* ei = (const int*)d_in[1];
    const float* W0 = (const float*)d_in[2];
    const float* b0 = (const float*)d_in[3];
    const float* W1 = (const float*)d_in[4];
    const float* b1 = (const float*)d_in[5];
    const float* W2 = (const float*)d_in[6];
    const float* b2 = (const float*)d_in[7];
    const float* mw1 = (const float*)d_in[8];
    const float* mb1 = (const float*)d_in[9];
    const float* mw2 = (const float*)d_in[10];
    const float* mb2 = (const float*)d_in[11];
    float* out = (float*)d_out;

    int N = in_sizes[0] / 128;
    int E = in_sizes[1] / 2;

    char* p = (char*)d_ws;
    auto alloc = [&](size_t bytes) {
        char* q = p;
        p += (bytes + 255) & ~size_t(255);
        return q;
    };
    float* bufA = (float*)alloc((size_t)N * 128 * 4);
    float* bufB = (float*)alloc((size_t)N * 128 * 4);
    int* cnt = (int*)alloc((size_t)N * 4);
    int* cursor = (int*)alloc((size_t)N * 4);
    int* offs = (int*)alloc((size_t)N * 4);
    float* dinv = (float*)alloc((size_t)N * 4);
    int* csr_src = (int*)alloc((size_t)E * 4);
    float* csr_w = (float*)alloc((size_t)E * 4);
    int* bsums = (int*)alloc(4096);
    int* flag = (int*)alloc(256);

    hipMemsetAsync(cnt, 0, (size_t)N * 4, stream);
    hipMemsetAsync(cursor, 0, (size_t)N * 4, stream);
    hipMemsetAsync(flag, 0, 4, stream);

    int gE = (E + 255) / 256;
    int gN = (N + 255) / 256;
    // detect: scan 2*E words (the first E index pairs) as int4 chunks
    int nchunks = (2 * E) / 4;
    k_detect<<<1024, 256, 0, stream>>>((const int4*)ei, nchunks, flag);
    k_count<<<gE, 256, 0, stream>>>(ei, E, cnt, flag);
    k_dinv<<<gN, 256, 0, stream>>>(cnt, dinv, N);
    int nb = (N + 1023) / 1024;
    k_scan_local<<<nb, 256, 0, stream>>>(cnt, N, offs, bsums);
    k_scan_bsums<<<1, 1, 0, stream>>>(bsums, nb);
    k_scan_add<<<gN, 256, 0, stream>>>(offs, bsums, N);
    k_fill<<<gE, 256, 0, stream>>>(ei, E, offs, cursor, dinv, csr_src, csr_w, flag);

    int gG = (N + 63) / 64;
    int gA = (N + 3) / 4;  // N waves, 4 per block

    // layer 0: t = x@W0 ; h0 = relu(agg(t)+b0)
    k_gemm<128, 128><<<gG, 256, 0, stream>>>(x, W0, bufA, N);
    k_aggregate<128, true><<<gA, 256, 0, stream>>>(bufA, offs, cnt, csr_src, csr_w, dinv, b0, bufB, N);
    // layer 1
    k_gemm<128, 128><<<gG, 256, 0, stream>>>(bufB, W1, bufA, N);
    k_aggregate<128, true><<<gA, 256, 0, stream>>>(bufA, offs, cnt, csr_src, csr_w, dinv, b1, bufB, N);
    // layer 2 (no relu)
    k_gemm<128, 64><<<gG, 256, 0, stream>>>(bufB, W2, bufA, N);
    k_aggregate<64, false><<<gA, 256, 0, stream>>>(bufA, offs, cnt, csr_src, csr_w, dinv, b2, bufB, N);
    // z = h2 @ mlp_w1 (linearity: ef@mlp_w1 = 0.5*(z_s+z_d))
    k_gemm<64, 64><<<gG, 256, 0, stream>>>(bufB, mw1, bufA, N);

    long long totalT = (long long)E * 16;
    int gM = (int)((totalT + 255) / 256);
    k_edge_mlp<<<gM, 256, 0, stream>>>(ei, E, bufA, mb1, mw2, mb2, out, flag);
}